// Round 7
// baseline (330.098 us; speedup 1.0000x reference)
//
#include <hip/hip_runtime.h>

// ============================================================================
// EncoderLayerWithAttn — B=4, S=1024, D=1024, H=16, dh=64, DFF=4096
// d_out = [ out fp32 (4M) | attn_weights fp32 (64M) ]
//
// Round 6: remove split-K entirely (was 256 MB of partial+LN traffic),
// fuse residual adds into GEMM epilogues, all GEMMs full-machine grids,
// XCD-aware bijective block swizzle (m157) on all GEMMs.
//   QKV / out-proj / FFN2 : gemm128 (round-2-verified core + resid + swizzle)
//   FFN1                  : gemm256 (round-5-verified core + swizzle)
//
// Workspace (96 MiB used of 112):
//   [0,24M)  qkvb bf16   -> h1b bf16 [0,32M) after attn
//   [24,32M) vtb bf16
//   [32,40M) srcb bf16
//   [40,48M) ctxb bf16
//   [48,56M) xb bf16 (LN1 out; FFN1 A; FFN2 resid)
//   [56,62M) w_in_b  [62,64M) w_outb  [64,72M) w1b  [72,80M) w2b
//   [80,88M) xsumb bf16   [88,96M) ffsumb bf16
// ============================================================================

#define DEVI __device__ __forceinline__

typedef __attribute__((ext_vector_type(4))) float f4;
typedef __attribute__((ext_vector_type(4))) float f32x4;
typedef __attribute__((ext_vector_type(8))) short s8;
typedef __attribute__((ext_vector_type(4))) unsigned short us4;
typedef unsigned short u16;

DEVI short bf16r(float f) {  // fp32 -> bf16 RNE
  unsigned u = __builtin_bit_cast(unsigned, f);
  unsigned r = (u + 0x7fffu + ((u >> 16) & 1u)) >> 16;
  return (short)(unsigned short)r;
}
DEVI float bf2f(u16 h) {
  unsigned u = ((unsigned)h) << 16;
  return __builtin_bit_cast(float, u);
}
DEVI s8 cvt8(f4 a, f4 b) {
  s8 r;
  r[0] = bf16r(a.x); r[1] = bf16r(a.y); r[2] = bf16r(a.z); r[3] = bf16r(a.w);
  r[4] = bf16r(b.x); r[5] = bf16r(b.y); r[6] = bf16r(b.z); r[7] = bf16r(b.w);
  return r;
}

DEVI void gload16(const void* g, void* l) {
  __builtin_amdgcn_global_load_lds(
      (const __attribute__((address_space(1))) unsigned int*)g,
      (__attribute__((address_space(3))) unsigned int*)l, 16, 0, 0);
}

#define BAR()   __builtin_amdgcn_s_barrier()
#define LGKM0() do { asm volatile("s_waitcnt lgkmcnt(0)" ::: "memory"); \
                     __builtin_amdgcn_sched_barrier(0); } while (0)
#define VM4()   do { asm volatile("s_waitcnt vmcnt(4)" ::: "memory"); \
                     __builtin_amdgcn_sched_barrier(0); } while (0)

// XCD-aware bijective swizzle (m157); requires total blocks % 8 == 0.
DEVI void xcd_remap(int& bx, int& by) {
  int nbx = gridDim.x, nby = gridDim.y;
  int hw = blockIdx.y * nbx + blockIdx.x;
  int qch = (nbx * nby) >> 3;
  int lid = (hw & 7) * qch + (hw >> 3);
  bx = lid % nbx; by = lid / nbx;
}

// ---------------------------------------------------------------------------
// gemm128: C[row,col] = A[row,K]@B[col,K]^T (+bias) (*qscale c<qcols) (relu)
// (+resid: RES 0=none 1=fp32 2=bf16), writes bf16. 128x128 tile, BK=64,
// 4 waves 2x2, global_load_lds(16B), granule-XOR swizzle both sides,
// __syncthreads double-barrier loop. Round-2-verified core.
template<int RES>
__global__ __launch_bounds__(256)
void gemm128(const u16* __restrict__ A, long lda,
             const u16* __restrict__ B, long ldb,
             u16* __restrict__ C, long ldc,
             const float* __restrict__ bias,
             const void* __restrict__ resid, long ldr, int K,
             int qcols, float qscale, int do_relu)
{
  __shared__ __align__(128) short As[128 * 64];
  __shared__ __align__(128) short Bs[128 * 64];

  int bx, by; xcd_remap(bx, by);
  int row0 = by * 128, col0 = bx * 128;
  int tid = threadIdx.x, lane = tid & 63, w = tid >> 6;
  int wr = w >> 1, wc = w & 1;

  const u16* Ab = A + (long)row0 * lda;
  const u16* Bb = B + (long)col0 * ldb;

  f32x4 acc[4][4] = {};

  for (int k0 = 0; k0 < K; k0 += 64) {
    if (k0) __syncthreads();
#pragma unroll
    for (int c = 0; c < 4; ++c) {
      int seg = w * 4 + c;
      int r = seg * 8 + (lane >> 3);
      int g = (lane & 7) ^ (r & 7);
      gload16(Ab + (long)r * lda + k0 + g * 8, (char*)As + seg * 1024);
    }
#pragma unroll
    for (int c = 0; c < 4; ++c) {
      int seg = w * 4 + c;
      int r = seg * 8 + (lane >> 3);
      int g = (lane & 7) ^ (r & 7);
      gload16(Bb + (long)r * ldb + k0 + g * 8, (char*)Bs + seg * 1024);
    }
    __syncthreads();

#pragma unroll
    for (int kk = 0; kk < 2; ++kk) {
      s8 af[4], bf[4];
      int lr = lane & 15, kg = kk * 4 + (lane >> 4);
#pragma unroll
      for (int i = 0; i < 4; ++i) {
        int R = wr * 64 + i * 16 + lr;
        af[i] = *(const s8*)((char*)As + R * 128 + ((kg ^ (R & 7)) * 16));
      }
#pragma unroll
      for (int j = 0; j < 4; ++j) {
        int R = wc * 64 + j * 16 + lr;
        bf[j] = *(const s8*)((char*)Bs + R * 128 + ((kg ^ (R & 7)) * 16));
      }
#pragma unroll
      for (int i = 0; i < 4; ++i)
#pragma unroll
        for (int j = 0; j < 4; ++j)
          acc[i][j] = __builtin_amdgcn_mfma_f32_16x16x32_bf16(af[i], bf[j], acc[i][j], 0, 0, 0);
    }
  }

  // epilogue: C/D layout col=lane&15, row=(lane>>4)*4+q
#pragma unroll
  for (int i = 0; i < 4; ++i) {
#pragma unroll
    for (int j = 0; j < 4; ++j) {
      int rb = row0 + wr * 64 + i * 16 + (lane >> 4) * 4;
      int c  = col0 + wc * 64 + j * 16 + (lane & 15);
      float bv = bias ? bias[c] : 0.0f;
      float sc = (c < qcols) ? qscale : 1.0f;
#pragma unroll
      for (int q = 0; q < 4; ++q) {
        float v = (acc[i][j][q] + bv) * sc;
        if (do_relu) v = fmaxf(v, 0.0f);
        long rr = rb + q;
        if constexpr (RES == 1) v += ((const float*)resid)[rr * ldr + c];
        if constexpr (RES == 2) v += bf2f(((const u16*)resid)[rr * ldr + c]);
        C[rr * ldc + c] = (u16)bf16r(v);
      }
    }
  }
}

// ---------------------------------------------------------------------------
// gemm256 (round-5-verified core): 256x256 tile, 512 thr (8 waves 2Mx4N),
// BK=32, ring-3 LDS, one phase per K-tile, VM4->BAR publish invariant,
// granule swizzle phys = g ^ ((row>>1)&3). Used for FFN1. Writes bf16.
__global__ __launch_bounds__(512, 2)
void gemm256(const u16* __restrict__ A, long lda,
             const u16* __restrict__ B, long ldb,
             u16* __restrict__ C, long ldc,
             const float* __restrict__ bias, int K, int do_relu)
{
  __shared__ __align__(128) char LDS[98304];  // A: 3x16KB @0, B: 3x16KB @48K

  const int tid = threadIdx.x, lane = tid & 63, w = tid >> 6;
  const int wr = w >> 2, wc = w & 3;
  int bx, by; xcd_remap(bx, by);
  const int row0 = by * 256, col0 = bx * 256;

  const u16* Ag = A + (long)row0 * lda;
  const u16* Bg = B + (long)col0 * ldb;

  const int NT = K >> 5;

  const int sr = (w << 4) + (lane >> 2);
  const int gsrc = (lane & 3) ^ ((sr >> 1) & 3);

  auto stageA = [&](int kt, int slot) {
#pragma unroll
    for (int h = 0; h < 2; ++h)
      gload16(Ag + (long)(h * 128 + sr) * lda + kt * 32 + gsrc * 8,
              LDS + slot * 16384 + h * 8192 + (w << 10));
  };
  auto stageB = [&](int kt, int slot) {
#pragma unroll
    for (int h = 0; h < 2; ++h)
      gload16(Bg + (long)(h * 128 + sr) * ldb + kt * 32 + gsrc * 8,
              LDS + 49152 + slot * 16384 + h * 8192 + (w << 10));
  };

  const int kg = lane >> 4, lr = lane & 15;
  auto rdA = [&](int buf, int fig, s8* aF) {
#pragma unroll
    for (int i = 0; i < 4; ++i) {
      int R = wr * 128 + (fig * 4 + i) * 16 + lr;
      aF[i] = *(const s8*)(LDS + buf * 16384 + R * 64 + ((kg ^ ((R >> 1) & 3)) << 4));
    }
  };
  auto rdB = [&](int buf, s8* bF) {
#pragma unroll
    for (int j = 0; j < 4; ++j) {
      int R = wc * 64 + j * 16 + lr;
      bF[j] = *(const s8*)(LDS + 49152 + buf * 16384 + R * 64 + ((kg ^ ((R >> 1) & 3)) << 4));
    }
  };

  f32x4 acc[8][4] = {};

  stageA(0, 0); stageB(0, 0);
  stageA(1, 1); stageB(1, 1);
  VM4();
  BAR();

  int buf = 0;
  for (int t = 0; t < NT; ++t) {
    int nbuf = buf + 2; if (nbuf >= 3) nbuf -= 3;
    int tc = (t + 2 < NT) ? t + 2 : NT - 1;
    s8 aF0[4], aF1[4], bF[4];

    stageA(tc, nbuf);
    stageB(tc, nbuf);
    rdB(buf, bF);
    rdA(buf, 0, aF0);
    rdA(buf, 1, aF1);
    BAR();
    LGKM0();
    __builtin_amdgcn_s_setprio(1);
#pragma unroll
    for (int i = 0; i < 4; ++i)
#pragma unroll
      for (int j = 0; j < 4; ++j)
        acc[i][j] = __builtin_amdgcn_mfma_f32_16x16x32_bf16(aF0[i], bF[j], acc[i][j], 0, 0, 0);
#pragma unroll
    for (int i = 0; i < 4; ++i)
#pragma unroll
      for (int j = 0; j < 4; ++j)
        acc[4 + i][j] = __builtin_amdgcn_mfma_f32_16x16x32_bf16(aF1[i], bF[j], acc[4 + i][j], 0, 0, 0);
    __builtin_amdgcn_s_setprio(0);
    VM4();   // certify tile t+1's loads retired (this wave) ...
    BAR();   // ... then publish to all waves
    buf = (buf == 2) ? 0 : buf + 1;
  }
  asm volatile("s_waitcnt vmcnt(0)" ::: "memory");

#pragma unroll
  for (int fi = 0; fi < 8; ++fi) {
#pragma unroll
    for (int fj = 0; fj < 4; ++fj) {
      int rb = row0 + wr * 128 + fi * 16 + (lane >> 4) * 4;
      int c  = col0 + wc * 64 + fj * 16 + lr;
      float bv = bias ? bias[c] : 0.0f;
#pragma unroll
      for (int q = 0; q < 4; ++q) {
        float v = acc[fi][fj][q] + bv;
        if (do_relu) v = fmaxf(v, 0.0f);
        C[(long)(rb + q) * ldc + c] = (u16)bf16r(v);
      }
    }
  }
}

// ---------------------------------------------------------------------------
// Fused attention (round-2 verified, unchanged).
__global__ __launch_bounds__(256)
void attn_fused(const u16* __restrict__ qkvb, const u16* __restrict__ vtb,
                float* __restrict__ attnW, u16* __restrict__ ctxb)
{
  __shared__ __align__(128) u16 Kt[128 * 64];
  __shared__ __align__(128) u16 Vt[64 * 128];
  __shared__ __align__(128) u16 Pt[4 * 32 * 128];

  int blk = blockIdx.x;
  int bh = blk >> 3, qt = blk & 7;
  int b = bh >> 4, h = bh & 15;
  int tid = threadIdx.x, lane = tid & 63, w = tid >> 6;

  const u16* Qg = qkvb + (long)b * 3145728 + (long)(qt * 128) * 3072 + h * 64;
#pragma unroll
  for (int c = 0; c < 4; ++c) {
    int seg = w * 4 + c;
    int r = seg * 8 + (lane >> 3);
    int g = (lane & 7) ^ (r & 7);
    gload16(Qg + (long)r * 3072 + g * 8, (char*)Kt + seg * 1024);
  }
  __syncthreads();
  s8 aq[2][2];
#pragma unroll
  for (int i = 0; i < 2; ++i)
#pragma unroll
    for (int kk = 0; kk < 2; ++kk) {
      int R = w * 32 + i * 16 + (lane & 15);
      int kgq = kk * 4 + (lane >> 4);
      aq[i][kk] = *(const s8*)((char*)Kt + R * 128 + ((kgq ^ (R & 7)) * 16));
    }

  const u16* Kbase = qkvb + (long)b * 3145728 + 1024 + h * 64;
  const u16* Vbase = vtb + (long)bh * 65536;

  float m[2][4], l[2][4];
#pragma unroll
  for (int i = 0; i < 2; ++i)
#pragma unroll
    for (int q = 0; q < 4; ++q) { m[i][q] = -1e30f; l[i][q] = 0.0f; }

  // ===== pass 1: running max + denom =====
  for (int kc = 0; kc < 8; ++kc) {
    __syncthreads();
#pragma unroll
    for (int c = 0; c < 4; ++c) {
      int seg = w * 4 + c;
      int r = seg * 8 + (lane >> 3);
      int g = (lane & 7) ^ (r & 7);
      gload16(Kbase + (long)(kc * 128 + r) * 3072 + g * 8, (char*)Kt + seg * 1024);
    }
    __syncthreads();

    f32x4 s[2][8] = {};
#pragma unroll
    for (int kk = 0; kk < 2; ++kk) {
      s8 bk[8];
      int kgq = kk * 4 + (lane >> 4);
#pragma unroll
      for (int j = 0; j < 8; ++j) {
        int R = j * 16 + (lane & 15);
        bk[j] = *(const s8*)((char*)Kt + R * 128 + ((kgq ^ (R & 7)) * 16));
      }
#pragma unroll
      for (int i = 0; i < 2; ++i)
#pragma unroll
        for (int j = 0; j < 8; ++j)
          s[i][j] = __builtin_amdgcn_mfma_f32_16x16x32_bf16(aq[i][kk], bk[j], s[i][j], 0, 0, 0);
    }

#pragma unroll
    for (int i = 0; i < 2; ++i)
#pragma unroll
      for (int q = 0; q < 4; ++q) {
        float mx = s[i][0][q];
#pragma unroll
        for (int j = 1; j < 8; ++j) mx = fmaxf(mx, s[i][j][q]);
        mx = fmaxf(mx, __shfl_xor(mx, 1));
        mx = fmaxf(mx, __shfl_xor(mx, 2));
        mx = fmaxf(mx, __shfl_xor(mx, 4));
        mx = fmaxf(mx, __shfl_xor(mx, 8));
        float mn = fmaxf(m[i][q], mx);
        float sum = 0.0f;
#pragma unroll
        for (int j = 0; j < 8; ++j) sum += __expf(s[i][j][q] - mn);
        sum += __shfl_xor(sum, 1);
        sum += __shfl_xor(sum, 2);
        sum += __shfl_xor(sum, 4);
        sum += __shfl_xor(sum, 8);
        l[i][q] = l[i][q] * __expf(m[i][q] - mn) + sum;
        m[i][q] = mn;
      }
  }

  float inv[2][4];
#pragma unroll
  for (int i = 0; i < 2; ++i)
#pragma unroll
    for (int q = 0; q < 4; ++q) inv[i][q] = 1.0f / l[i][q];

  // ===== pass 2: P write + PV =====
  f32x4 o_[2][4] = {};
  float* aw = attnW + (long)bh * 1048576 + (long)(qt * 128) * 1024;
  u16* Pw = Pt + w * 4096;

  for (int kc = 0; kc < 8; ++kc) {
    __syncthreads();
#pragma unroll
    for (int c = 0; c < 4; ++c) {
      int seg = w * 4 + c;
      int r = seg * 8 + (lane >> 3);
      int g = (lane & 7) ^ (r & 7);
      gload16(Kbase + (long)(kc * 128 + r) * 3072 + g * 8, (char*)Kt + seg * 1024);
    }
#pragma unroll
    for (int c = 0; c < 4; ++c) {
      int seg = w * 4 + c;
      int r = seg * 4 + (lane >> 4);
      int g = (lane & 15) ^ (r & 7);
      gload16(Vbase + (long)r * 1024 + kc * 128 + g * 8, (char*)Vt + seg * 1024);
    }
    __syncthreads();

    f32x4 s[2][8] = {};
#pragma unroll
    for (int kk = 0; kk < 2; ++kk) {
      s8 bk[8];
      int kgq = kk * 4 + (lane >> 4);
#pragma unroll
      for (int j = 0; j < 8; ++j) {
        int R = j * 16 + (lane & 15);
        bk[j] = *(const s8*)((char*)Kt + R * 128 + ((kgq ^ (R & 7)) * 16));
      }
#pragma unroll
      for (int i = 0; i < 2; ++i)
#pragma unroll
        for (int j = 0; j < 8; ++j)
          s[i][j] = __builtin_amdgcn_mfma_f32_16x16x32_bf16(aq[i][kk], bk[j], s[i][j], 0, 0, 0);
    }

#pragma unroll
    for (int i = 0; i < 2; ++i)
#pragma unroll
      for (int j = 0; j < 8; ++j)
#pragma unroll
        for (int q = 0; q < 4; ++q) {
          float p = __expf(s[i][j][q] - m[i][q]) * inv[i][q];
          int R = i * 16 + (lane >> 4) * 4 + q;
          int C = j * 16 + (lane & 15);
          aw[(long)(w * 32 + R) * 1024 + kc * 128 + C] = p;
          *(u16*)((char*)Pw + R * 256 + (((C >> 3) ^ (R & 7)) * 16) + (C & 7) * 2)
              = (u16)bf16r(p);
        }

#pragma unroll
    for (int kks = 0; kks < 4; ++kks) {
      int kgq = kks * 4 + (lane >> 4);
      s8 pa[2], bv[4];
#pragma unroll
      for (int i = 0; i < 2; ++i) {
        int R = i * 16 + (lane & 15);
        pa[i] = *(const s8*)((char*)Pw + R * 256 + ((kgq ^ (R & 7)) * 16));
      }
#pragma unroll
      for (int j = 0; j < 4; ++j) {
        int R = j * 16 + (lane & 15);
        bv[j] = *(const s8*)((char*)Vt + R * 256 + ((kgq ^ (R & 7)) * 16));
      }
#pragma unroll
      for (int i = 0; i < 2; ++i)
#pragma unroll
        for (int j = 0; j < 4; ++j)
          o_[i][j] = __builtin_amdgcn_mfma_f32_16x16x32_bf16(pa[i], bv[j], o_[i][j], 0, 0, 0);
    }
  }

#pragma unroll
  for (int i = 0; i < 2; ++i)
#pragma unroll
    for (int j = 0; j < 4; ++j)
#pragma unroll
      for (int q = 0; q < 4; ++q) {
        int R = w * 32 + i * 16 + (lane >> 4) * 4 + q;
        int col = h * 64 + j * 16 + (lane & 15);
        ctxb[(long)(b * 1024 + qt * 128 + R) * 1024 + col] = (u16)bf16r(o_[i][j][q]);
      }
}

// ---------------------------------------------------------------------------
DEVI float blockSum(float v, float* sh) {
#pragma unroll
  for (int o = 32; o > 0; o >>= 1) v += __shfl_xor(v, o);
  int w = threadIdx.x >> 6;
  __syncthreads();
  if ((threadIdx.x & 63) == 0) sh[w] = v;
  __syncthreads();
  return (sh[0] + sh[1]) + (sh[2] + sh[3]);
}

// LayerNorm over rows of 1024, bf16 input; writes fp32 and/or bf16.
__global__ __launch_bounds__(256)
void ln_rows_b(const u16* __restrict__ in, const float* __restrict__ g,
               const float* __restrict__ be,
               float* __restrict__ outf, u16* __restrict__ outb)
{
  __shared__ float sh[4];
  long row = blockIdx.x;
  int t = threadIdx.x;
  long off = row * 1024 + t * 4;
  us4 rp = *(const us4*)(in + off);
  f4 v;
  v.x = bf2f(rp.x); v.y = bf2f(rp.y); v.z = bf2f(rp.z); v.w = bf2f(rp.w);
  float s = (v.x + v.y) + (v.z + v.w);
  s = blockSum(s, sh);
  float mu = s * (1.0f / 1024.0f);
  f4 d = v - mu;
  float s2 = (d.x * d.x + d.y * d.y) + (d.z * d.z + d.w * d.w);
  s2 = blockSum(s2, sh);
  float rs = rsqrtf(s2 * (1.0f / 1024.0f) + 1e-5f);
  f4 gg = *(const f4*)(g + t * 4);
  f4 bb = *(const f4*)(be + t * 4);
  f4 o = d * rs * gg + bb;
  if (outf) *(f4*)(outf + off) = o;
  if (outb) {
    us4 ob;
    ob.x = (u16)bf16r(o.x); ob.y = (u16)bf16r(o.y);
    ob.z = (u16)bf16r(o.z); ob.w = (u16)bf16r(o.w);
    *(us4*)(outb + off) = ob;
  }
}

// all five fp32->bf16 conversions in one launch
__global__ __launch_bounds__(256)
void cvt_all(const float* __restrict__ s0, const float* __restrict__ s1,
             const float* __restrict__ s2, const float* __restrict__ s3,
             const float* __restrict__ s4,
             u16* __restrict__ d0, u16* __restrict__ d1, u16* __restrict__ d2,
             u16* __restrict__ d3, u16* __restrict__ d4)
{
  int bi = blockIdx.x;
  const float* s; u16* d; int base;
  if      (bi < 2048) { s = s0; d = d0; base = bi; }
  else if (bi < 3584) { s = s1; d = d1; base = bi - 2048; }
  else if (bi < 4096) { s = s2; d = d2; base = bi - 3584; }
  else if (bi < 6144) { s = s3; d = d3; base = bi - 4096; }
  else                { s = s4; d = d4; base = bi - 6144; }
  long i = ((long)base * 256 + threadIdx.x) * 8;
  f4 a = *(const f4*)(s + i);
  f4 b = *(const f4*)(s + i + 4);
  *(s8*)(d + i) = cvt8(a, b);
}

// vt[bh][d][s] = qkvb[b, s, 2048 + h*64 + d]   (bf16)
__global__ __launch_bounds__(256)
void transpose_v(const u16* __restrict__ qkv, u16* __restrict__ vt) {
  __shared__ u16 tile[64][72];
  int blk = blockIdx.x, bh = blk >> 4, st = blk & 15;
  int b = bh >> 4, h = bh & 15, s0 = st * 64;
  const u16* gq = qkv + (long)b * 1024 * 3072 + 2048 + (long)h * 64;
  int t = threadIdx.x;
  int sl = t >> 4, dq = (t & 15) * 4;
#pragma unroll
  for (int it = 0; it < 4; ++it) {
    int s = it * 16 + sl;
    us4 v = *(const us4*)(gq + (long)(s0 + s) * 3072 + dq);
    tile[dq + 0][s] = v.x; tile[dq + 1][s] = v.y;
    tile[dq + 2][s] = v.z; tile[dq + 3][s] = v.w;
  }
  __syncthreads();
  u16* o = vt + (long)bh * 65536 + s0;
  int dl = t >> 4, sq = (t & 15) * 4;
#pragma unroll
  for (int it = 0; it < 4; ++it) {
    int d = it * 16 + dl;
    us4 v;
    v.x = tile[d][sq + 0]; v.y = tile[d][sq + 1];
    v.z = tile[d][sq + 2]; v.w = tile[d][sq + 3];
    *(us4*)(o + (long)d * 1024 + sq) = v;
  }
}

// ============================================================================
extern "C" void kernel_launch(void* const* d_in, const int* in_sizes, int n_in,
                              void* d_out, int out_size, void* d_ws, size_t ws_size,
                              hipStream_t stream)
{
  (void)in_sizes; (void)n_in; (void)out_size; (void)ws_size;
  const float* src   = (const float*)d_in[0];
  const float* w_in  = (const float*)d_in[1];
  const float* b_in  = (const float*)d_in[2];
  const float* w_out = (const float*)d_in[3];
  const float* b_out = (const float*)d_in[4];
  const float* w1    = (const float*)d_in[5];
  const float* b1    = (const float*)d_in[6];
  const float* w2    = (const float*)d_in[7];
  const float* b2    = (const float*)d_in[8];
  const float* g1    = (const float*)d_in[9];
  const float* be1   = (const float*)d_in[10];
  const float* g2    = (const float*)d_in[11];
  const float* be2   = (const float*)d_in[12];

  float* out   = (float*)d_out;
  float* attnW = out + (long)4 * 1024 * 1024;

  char* ws = (char*)d_ws;
  u16*   qkvb   = (u16*)(ws);                    // [4096,3072] bf16
  u16*   vtb    = (u16*)(ws + 25165824);         // [64][64][1024]
  u16*   srcb   = (u16*)(ws + 33554432);
  u16*   ctxb   = (u16*)(ws + 41943040);
  u16*   xb     = (u16*)(ws + 50331648);
  u16*   w_in_b = (u16*)(ws + 58720256);
  u16*   w_outb = (u16*)(ws + 65011712);
  u16*   w1b    = (u16*)(ws + 67108864);
  u16*   w2b    = (u16*)(ws + 75497472);
  u16*   xsumb  = (u16*)(ws + 83886080);         // [4096,1024] bf16
  u16*   ffsumb = (u16*)(ws + 92274688);         // [4096,1024] bf16
  u16*   h1b    = (u16*)(ws);                    // [4096,4096] bf16 [0,32M)

  // 0. conversions
  cvt_all<<<dim3(8192), 256, 0, stream>>>(src, w_in, w_out, w1, w2,
                                          srcb, w_in_b, w_outb, w1b, w2b);

  // 1. qkvb = bf16(src @ w_in^T + b_in), q-cols scaled by 0.125
  gemm128<0><<<dim3(24, 32), 256, 0, stream>>>(
      srcb, 1024, w_in_b, 1024, qkvb, 3072,
      b_in, nullptr, 0, 1024, 1024, 0.125f, 0);

  // 2. vtb = V^T per (b,h)
  transpose_v<<<dim3(1024), 256, 0, stream>>>(qkvb, vtb);

  // 3. fused attention: attnW fp32 + ctxb bf16
  attn_fused<<<dim3(512), 256, 0, stream>>>(qkvb, vtb, attnW, ctxb);

  // 4. xsumb = bf16(ctx @ w_out^T + b_out + src)   (resid fused, no split-K)
  gemm128<1><<<dim3(8, 32), 256, 0, stream>>>(
      ctxb, 1024, w_outb, 1024, xsumb, 1024,
      b_out, src, 1024, 1024, 0, 1.0f, 0);

  // 5. xb = bf16(LN1(xsumb))
  ln_rows_b<<<dim3(4096), 256, 0, stream>>>(xsumb, g1, be1, nullptr, xb);

  // 6. h1b = bf16(relu(x @ w1^T + b1))   (256-tile, exactly 256 blocks)
  gemm256<<<dim3(16, 16), 512, 0, stream>>>(
      xb, 1024, w1b, 1024, h1b, 4096, b1, 1024, 1);

  // 7. ffsumb = bf16(h1 @ w2^T + b2 + xb)   (resid fused, no split-K)
  gemm128<2><<<dim3(8, 32), 256, 0, stream>>>(
      h1b, 4096, w2b, 4096, ffsumb, 1024,
      b2, xb, 1024, 4096, 0, 1.0f, 0);

  // 8. out = LN2(ffsumb)  (fp32)
  ln_rows_b<<<dim3(4096), 256, 0, stream>>>(ffsumb, g2, be2, out, nullptr);
}

// Round 8
// 321.521 us; speedup vs baseline: 1.0267x; 1.0267x over previous
//
#include <hip/hip_runtime.h>

// ============================================================================
// EncoderLayerWithAttn — B=4, S=1024, D=1024, H=16, dh=64, DFF=4096
// d_out = [ out fp32 (4M) | attn_weights fp32 (64M) ]
//
// Round 7: occupancy + store-path round.
//  - out-proj & FFN2: gemm128 split-K=2 (512 blocks = 2/CU; fp32 partials are
//    L3-resident), combine fused into ln_combine (round-2-verified).
//  - attn_fused: attnW written via Pt-LDS readback as vectorized dwordx4
//    row segments (bf16-rounded, consistent with PV's P).
//  - QKV gemm128 (768 blocks), FFN1 gemm256: unchanged verified cores.
//
// Workspace (112 MiB):
//   [0,24M)  qkvb bf16  -> Q0[0,16M) Q1[16,32M) partials -> h1b bf16 [0,32M)
//   [24,32M) vtb bf16
//   [32,40M) srcb bf16
//   [40,48M) ctxb bf16
//   [48,56M) xb bf16
//   [56,62M) w_in_b  [62,64M) w_outb  [64,72M) w1b  [72,80M) w2b
//   [80,96M) R0 fp32   [96,112M) R1 fp32
// ============================================================================

#define DEVI __device__ __forceinline__

typedef __attribute__((ext_vector_type(4))) float f4;
typedef __attribute__((ext_vector_type(4))) float f32x4;
typedef __attribute__((ext_vector_type(8))) short s8;
typedef __attribute__((ext_vector_type(4))) unsigned short us4;
typedef unsigned short u16;

DEVI short bf16r(float f) {  // fp32 -> bf16 RNE
  unsigned u = __builtin_bit_cast(unsigned, f);
  unsigned r = (u + 0x7fffu + ((u >> 16) & 1u)) >> 16;
  return (short)(unsigned short)r;
}
DEVI float bf2f(u16 h) {
  unsigned u = ((unsigned)h) << 16;
  return __builtin_bit_cast(float, u);
}
DEVI s8 cvt8(f4 a, f4 b) {
  s8 r;
  r[0] = bf16r(a.x); r[1] = bf16r(a.y); r[2] = bf16r(a.z); r[3] = bf16r(a.w);
  r[4] = bf16r(b.x); r[5] = bf16r(b.y); r[6] = bf16r(b.z); r[7] = bf16r(b.w);
  return r;
}

DEVI void gload16(const void* g, void* l) {
  __builtin_amdgcn_global_load_lds(
      (const __attribute__((address_space(1))) unsigned int*)g,
      (__attribute__((address_space(3))) unsigned int*)l, 16, 0, 0);
}

#define BAR()   __builtin_amdgcn_s_barrier()
#define LGKM0() do { asm volatile("s_waitcnt lgkmcnt(0)" ::: "memory"); \
                     __builtin_amdgcn_sched_barrier(0); } while (0)
#define VM4()   do { asm volatile("s_waitcnt vmcnt(4)" ::: "memory"); \
                     __builtin_amdgcn_sched_barrier(0); } while (0)

// XCD-aware bijective swizzle (m157); requires total blocks % 8 == 0.
DEVI void xcd_remap(int& bx, int& by) {
  int nbx = gridDim.x, nby = gridDim.y;
  int hw = blockIdx.y * nbx + blockIdx.x;
  int qch = (nbx * nby) >> 3;
  int lid = (hw & 7) * qch + (hw >> 3);
  bx = lid % nbx; by = lid / nbx;
}

// ---------------------------------------------------------------------------
// gemm128 (round-2-verified core): bf16 out, bias/qscale/relu epilogue.
__global__ __launch_bounds__(256)
void gemm128(const u16* __restrict__ A, long lda,
             const u16* __restrict__ B, long ldb,
             u16* __restrict__ C, long ldc,
             const float* __restrict__ bias, int K,
             int qcols, float qscale)
{
  __shared__ __align__(128) short As[128 * 64];
  __shared__ __align__(128) short Bs[128 * 64];

  int bx, by; xcd_remap(bx, by);
  int row0 = by * 128, col0 = bx * 128;
  int tid = threadIdx.x, lane = tid & 63, w = tid >> 6;
  int wr = w >> 1, wc = w & 1;

  const u16* Ab = A + (long)row0 * lda;
  const u16* Bb = B + (long)col0 * ldb;

  f32x4 acc[4][4] = {};

  for (int k0 = 0; k0 < K; k0 += 64) {
    if (k0) __syncthreads();
#pragma unroll
    for (int c = 0; c < 4; ++c) {
      int seg = w * 4 + c;
      int r = seg * 8 + (lane >> 3);
      int g = (lane & 7) ^ (r & 7);
      gload16(Ab + (long)r * lda + k0 + g * 8, (char*)As + seg * 1024);
    }
#pragma unroll
    for (int c = 0; c < 4; ++c) {
      int seg = w * 4 + c;
      int r = seg * 8 + (lane >> 3);
      int g = (lane & 7) ^ (r & 7);
      gload16(Bb + (long)r * ldb + k0 + g * 8, (char*)Bs + seg * 1024);
    }
    __syncthreads();

#pragma unroll
    for (int kk = 0; kk < 2; ++kk) {
      s8 af[4], bf[4];
      int lr = lane & 15, kg = kk * 4 + (lane >> 4);
#pragma unroll
      for (int i = 0; i < 4; ++i) {
        int R = wr * 64 + i * 16 + lr;
        af[i] = *(const s8*)((char*)As + R * 128 + ((kg ^ (R & 7)) * 16));
      }
#pragma unroll
      for (int j = 0; j < 4; ++j) {
        int R = wc * 64 + j * 16 + lr;
        bf[j] = *(const s8*)((char*)Bs + R * 128 + ((kg ^ (R & 7)) * 16));
      }
#pragma unroll
      for (int i = 0; i < 4; ++i)
#pragma unroll
        for (int j = 0; j < 4; ++j)
          acc[i][j] = __builtin_amdgcn_mfma_f32_16x16x32_bf16(af[i], bf[j], acc[i][j], 0, 0, 0);
    }
  }

#pragma unroll
  for (int i = 0; i < 4; ++i) {
#pragma unroll
    for (int j = 0; j < 4; ++j) {
      int rb = row0 + wr * 64 + i * 16 + (lane >> 4) * 4;
      int c  = col0 + wc * 64 + j * 16 + (lane & 15);
      float bv = bias ? bias[c] : 0.0f;
      float sc = (c < qcols) ? qscale : 1.0f;
#pragma unroll
      for (int q = 0; q < 4; ++q) {
        float v = (acc[i][j][q] + bv) * sc;
        C[(long)(rb + q) * ldc + c] = (u16)bf16r(v);
      }
    }
  }
}

// gemm128s: split-K variant, fp32 partial out at C + z*4194304 (no epilogue).
__global__ __launch_bounds__(256)
void gemm128s(const u16* __restrict__ A, long lda, long sAz,
              const u16* __restrict__ B, long ldb, long sBz,
              float* __restrict__ C, long ldc, int K)
{
  __shared__ __align__(128) short As[128 * 64];
  __shared__ __align__(128) short Bs[128 * 64];

  int bx, by; xcd_remap(bx, by);
  int z = blockIdx.z;
  int row0 = by * 128, col0 = bx * 128;
  int tid = threadIdx.x, lane = tid & 63, w = tid >> 6;
  int wr = w >> 1, wc = w & 1;

  const u16* Ab = A + (long)z * sAz + (long)row0 * lda;
  const u16* Bb = B + (long)z * sBz + (long)col0 * ldb;
  float* Cz = C + (long)z * 4194304;

  f32x4 acc[4][4] = {};

  for (int k0 = 0; k0 < K; k0 += 64) {
    if (k0) __syncthreads();
#pragma unroll
    for (int c = 0; c < 4; ++c) {
      int seg = w * 4 + c;
      int r = seg * 8 + (lane >> 3);
      int g = (lane & 7) ^ (r & 7);
      gload16(Ab + (long)r * lda + k0 + g * 8, (char*)As + seg * 1024);
    }
#pragma unroll
    for (int c = 0; c < 4; ++c) {
      int seg = w * 4 + c;
      int r = seg * 8 + (lane >> 3);
      int g = (lane & 7) ^ (r & 7);
      gload16(Bb + (long)r * ldb + k0 + g * 8, (char*)Bs + seg * 1024);
    }
    __syncthreads();

#pragma unroll
    for (int kk = 0; kk < 2; ++kk) {
      s8 af[4], bf[4];
      int lr = lane & 15, kg = kk * 4 + (lane >> 4);
#pragma unroll
      for (int i = 0; i < 4; ++i) {
        int R = wr * 64 + i * 16 + lr;
        af[i] = *(const s8*)((char*)As + R * 128 + ((kg ^ (R & 7)) * 16));
      }
#pragma unroll
      for (int j = 0; j < 4; ++j) {
        int R = wc * 64 + j * 16 + lr;
        bf[j] = *(const s8*)((char*)Bs + R * 128 + ((kg ^ (R & 7)) * 16));
      }
#pragma unroll
      for (int i = 0; i < 4; ++i)
#pragma unroll
        for (int j = 0; j < 4; ++j)
          acc[i][j] = __builtin_amdgcn_mfma_f32_16x16x32_bf16(af[i], bf[j], acc[i][j], 0, 0, 0);
    }
  }

#pragma unroll
  for (int i = 0; i < 4; ++i) {
#pragma unroll
    for (int j = 0; j < 4; ++j) {
      int rb = row0 + wr * 64 + i * 16 + (lane >> 4) * 4;
      int c  = col0 + wc * 64 + j * 16 + (lane & 15);
#pragma unroll
      for (int q = 0; q < 4; ++q)
        Cz[(long)(rb + q) * ldc + c] = acc[i][j][q];
    }
  }
}

// ---------------------------------------------------------------------------
// gemm256 (round-5-verified core): FFN1 only (16x16 grid = 256 blocks).
__global__ __launch_bounds__(512, 2)
void gemm256(const u16* __restrict__ A, long lda,
             const u16* __restrict__ B, long ldb,
             u16* __restrict__ C, long ldc,
             const float* __restrict__ bias, int K, int do_relu)
{
  __shared__ __align__(128) char LDS[98304];

  const int tid = threadIdx.x, lane = tid & 63, w = tid >> 6;
  const int wr = w >> 2, wc = w & 3;
  int bx, by; xcd_remap(bx, by);
  const int row0 = by * 256, col0 = bx * 256;

  const u16* Ag = A + (long)row0 * lda;
  const u16* Bg = B + (long)col0 * ldb;

  const int NT = K >> 5;

  const int sr = (w << 4) + (lane >> 2);
  const int gsrc = (lane & 3) ^ ((sr >> 1) & 3);

  auto stageA = [&](int kt, int slot) {
#pragma unroll
    for (int h = 0; h < 2; ++h)
      gload16(Ag + (long)(h * 128 + sr) * lda + kt * 32 + gsrc * 8,
              LDS + slot * 16384 + h * 8192 + (w << 10));
  };
  auto stageB = [&](int kt, int slot) {
#pragma unroll
    for (int h = 0; h < 2; ++h)
      gload16(Bg + (long)(h * 128 + sr) * ldb + kt * 32 + gsrc * 8,
              LDS + 49152 + slot * 16384 + h * 8192 + (w << 10));
  };

  const int kg = lane >> 4, lr = lane & 15;
  auto rdA = [&](int buf, int fig, s8* aF) {
#pragma unroll
    for (int i = 0; i < 4; ++i) {
      int R = wr * 128 + (fig * 4 + i) * 16 + lr;
      aF[i] = *(const s8*)(LDS + buf * 16384 + R * 64 + ((kg ^ ((R >> 1) & 3)) << 4));
    }
  };
  auto rdB = [&](int buf, s8* bF) {
#pragma unroll
    for (int j = 0; j < 4; ++j) {
      int R = wc * 64 + j * 16 + lr;
      bF[j] = *(const s8*)(LDS + 49152 + buf * 16384 + R * 64 + ((kg ^ ((R >> 1) & 3)) << 4));
    }
  };

  f32x4 acc[8][4] = {};

  stageA(0, 0); stageB(0, 0);
  stageA(1, 1); stageB(1, 1);
  VM4();
  BAR();

  int buf = 0;
  for (int t = 0; t < NT; ++t) {
    int nbuf = buf + 2; if (nbuf >= 3) nbuf -= 3;
    int tc = (t + 2 < NT) ? t + 2 : NT - 1;
    s8 aF0[4], aF1[4], bF[4];

    stageA(tc, nbuf);
    stageB(tc, nbuf);
    rdB(buf, bF);
    rdA(buf, 0, aF0);
    rdA(buf, 1, aF1);
    BAR();
    LGKM0();
    __builtin_amdgcn_s_setprio(1);
#pragma unroll
    for (int i = 0; i < 4; ++i)
#pragma unroll
      for (int j = 0; j < 4; ++j)
        acc[i][j] = __builtin_amdgcn_mfma_f32_16x16x32_bf16(aF0[i], bF[j], acc[i][j], 0, 0, 0);
#pragma unroll
    for (int i = 0; i < 4; ++i)
#pragma unroll
      for (int j = 0; j < 4; ++j)
        acc[4 + i][j] = __builtin_amdgcn_mfma_f32_16x16x32_bf16(aF1[i], bF[j], acc[4 + i][j], 0, 0, 0);
    __builtin_amdgcn_s_setprio(0);
    VM4();
    BAR();
    buf = (buf == 2) ? 0 : buf + 1;
  }
  asm volatile("s_waitcnt vmcnt(0)" ::: "memory");

#pragma unroll
  for (int fi = 0; fi < 8; ++fi) {
#pragma unroll
    for (int fj = 0; fj < 4; ++fj) {
      int rb = row0 + wr * 128 + fi * 16 + (lane >> 4) * 4;
      int c  = col0 + wc * 64 + fj * 16 + lr;
      float bv = bias ? bias[c] : 0.0f;
#pragma unroll
      for (int q = 0; q < 4; ++q) {
        float v = acc[fi][fj][q] + bv;
        if (do_relu) v = fmaxf(v, 0.0f);
        C[(long)(rb + q) * ldc + c] = (u16)bf16r(v);
      }
    }
  }
}

// ---------------------------------------------------------------------------
// Fused attention. Round-2-verified structure; round-7 change: attnW written
// via Pt readback (vectorized dwordx4, bf16-rounded — consistent with PV).
__global__ __launch_bounds__(256)
void attn_fused(const u16* __restrict__ qkvb, const u16* __restrict__ vtb,
                float* __restrict__ attnW, u16* __restrict__ ctxb)
{
  __shared__ __align__(128) u16 Kt[128 * 64];
  __shared__ __align__(128) u16 Vt[64 * 128];
  __shared__ __align__(128) u16 Pt[4 * 32 * 128];

  int blk = blockIdx.x;
  int bh = blk >> 3, qt = blk & 7;
  int b = bh >> 4, h = bh & 15;
  int tid = threadIdx.x, lane = tid & 63, w = tid >> 6;

  const u16* Qg = qkvb + (long)b * 3145728 + (long)(qt * 128) * 3072 + h * 64;
#pragma unroll
  for (int c = 0; c < 4; ++c) {
    int seg = w * 4 + c;
    int r = seg * 8 + (lane >> 3);
    int g = (lane & 7) ^ (r & 7);
    gload16(Qg + (long)r * 3072 + g * 8, (char*)Kt + seg * 1024);
  }
  __syncthreads();
  s8 aq[2][2];
#pragma unroll
  for (int i = 0; i < 2; ++i)
#pragma unroll
    for (int kk = 0; kk < 2; ++kk) {
      int R = w * 32 + i * 16 + (lane & 15);
      int kgq = kk * 4 + (lane >> 4);
      aq[i][kk] = *(const s8*)((char*)Kt + R * 128 + ((kgq ^ (R & 7)) * 16));
    }

  const u16* Kbase = qkvb + (long)b * 3145728 + 1024 + h * 64;
  const u16* Vbase = vtb + (long)bh * 65536;

  float m[2][4], l[2][4];
#pragma unroll
  for (int i = 0; i < 2; ++i)
#pragma unroll
    for (int q = 0; q < 4; ++q) { m[i][q] = -1e30f; l[i][q] = 0.0f; }

  // ===== pass 1: running max + denom =====
  for (int kc = 0; kc < 8; ++kc) {
    __syncthreads();
#pragma unroll
    for (int c = 0; c < 4; ++c) {
      int seg = w * 4 + c;
      int r = seg * 8 + (lane >> 3);
      int g = (lane & 7) ^ (r & 7);
      gload16(Kbase + (long)(kc * 128 + r) * 3072 + g * 8, (char*)Kt + seg * 1024);
    }
    __syncthreads();

    f32x4 s[2][8] = {};
#pragma unroll
    for (int kk = 0; kk < 2; ++kk) {
      s8 bk[8];
      int kgq = kk * 4 + (lane >> 4);
#pragma unroll
      for (int j = 0; j < 8; ++j) {
        int R = j * 16 + (lane & 15);
        bk[j] = *(const s8*)((char*)Kt + R * 128 + ((kgq ^ (R & 7)) * 16));
      }
#pragma unroll
      for (int i = 0; i < 2; ++i)
#pragma unroll
        for (int j = 0; j < 8; ++j)
          s[i][j] = __builtin_amdgcn_mfma_f32_16x16x32_bf16(aq[i][kk], bk[j], s[i][j], 0, 0, 0);
    }

#pragma unroll
    for (int i = 0; i < 2; ++i)
#pragma unroll
      for (int q = 0; q < 4; ++q) {
        float mx = s[i][0][q];
#pragma unroll
        for (int j = 1; j < 8; ++j) mx = fmaxf(mx, s[i][j][q]);
        mx = fmaxf(mx, __shfl_xor(mx, 1));
        mx = fmaxf(mx, __shfl_xor(mx, 2));
        mx = fmaxf(mx, __shfl_xor(mx, 4));
        mx = fmaxf(mx, __shfl_xor(mx, 8));
        float mn = fmaxf(m[i][q], mx);
        float sum = 0.0f;
#pragma unroll
        for (int j = 0; j < 8; ++j) sum += __expf(s[i][j][q] - mn);
        sum += __shfl_xor(sum, 1);
        sum += __shfl_xor(sum, 2);
        sum += __shfl_xor(sum, 4);
        sum += __shfl_xor(sum, 8);
        l[i][q] = l[i][q] * __expf(m[i][q] - mn) + sum;
        m[i][q] = mn;
      }
  }

  float inv[2][4];
#pragma unroll
  for (int i = 0; i < 2; ++i)
#pragma unroll
    for (int q = 0; q < 4; ++q) inv[i][q] = 1.0f / l[i][q];

  // ===== pass 2: P (bf16) -> Pt; PV; vectorized attnW store =====
  f32x4 o_[2][4] = {};
  float* aw = attnW + (long)bh * 1048576 + (long)(qt * 128) * 1024;
  u16* Pw = Pt + w * 4096;

  for (int kc = 0; kc < 8; ++kc) {
    __syncthreads();
#pragma unroll
    for (int c = 0; c < 4; ++c) {
      int seg = w * 4 + c;
      int r = seg * 8 + (lane >> 3);
      int g = (lane & 7) ^ (r & 7);
      gload16(Kbase + (long)(kc * 128 + r) * 3072 + g * 8, (char*)Kt + seg * 1024);
    }
#pragma unroll
    for (int c = 0; c < 4; ++c) {
      int seg = w * 4 + c;
      int r = seg * 4 + (lane >> 4);
      int g = (lane & 15) ^ (r & 7);
      gload16(Vbase + (long)r * 1024 + kc * 128 + g * 8, (char*)Vt + seg * 1024);
    }
    __syncthreads();

    f32x4 s[2][8] = {};
#pragma unroll
    for (int kk = 0; kk < 2; ++kk) {
      s8 bk[8];
      int kgq = kk * 4 + (lane >> 4);
#pragma unroll
      for (int j = 0; j < 8; ++j) {
        int R = j * 16 + (lane & 15);
        bk[j] = *(const s8*)((char*)Kt + R * 128 + ((kgq ^ (R & 7)) * 16));
      }
#pragma unroll
      for (int i = 0; i < 2; ++i)
#pragma unroll
        for (int j = 0; j < 8; ++j)
          s[i][j] = __builtin_amdgcn_mfma_f32_16x16x32_bf16(aq[i][kk], bk[j], s[i][j], 0, 0, 0);
    }

    // P = exp(s-m)*inv -> bf16 into per-wave swizzled Pt only
#pragma unroll
    for (int i = 0; i < 2; ++i)
#pragma unroll
      for (int j = 0; j < 8; ++j)
#pragma unroll
        for (int q = 0; q < 4; ++q) {
          float p = __expf(s[i][j][q] - m[i][q]) * inv[i][q];
          int R = i * 16 + (lane >> 4) * 4 + q;
          int C = j * 16 + (lane & 15);
          *(u16*)((char*)Pw + R * 256 + (((C >> 3) ^ (R & 7)) * 16) + (C & 7) * 2)
              = (u16)bf16r(p);
        }

    // PV: contraction over 128 keys
#pragma unroll
    for (int kks = 0; kks < 4; ++kks) {
      int kgq = kks * 4 + (lane >> 4);
      s8 pa[2], bv[4];
#pragma unroll
      for (int i = 0; i < 2; ++i) {
        int R = i * 16 + (lane & 15);
        pa[i] = *(const s8*)((char*)Pw + R * 256 + ((kgq ^ (R & 7)) * 16));
      }
#pragma unroll
      for (int j = 0; j < 4; ++j) {
        int R = j * 16 + (lane & 15);
        bv[j] = *(const s8*)((char*)Vt + R * 256 + ((kgq ^ (R & 7)) * 16));
      }
#pragma unroll
      for (int i = 0; i < 2; ++i)
#pragma unroll
        for (int j = 0; j < 4; ++j)
          o_[i][j] = __builtin_amdgcn_mfma_f32_16x16x32_bf16(pa[i], bv[j], o_[i][j], 0, 0, 0);
    }

    // vectorized attnW store from Pt (8 lanes x 128 B contiguous per row)
#pragma unroll
    for (int it = 0; it < 4; ++it) {
      int R2 = it * 8 + (lane >> 3);
      int gx = lane & 7;
      float* dst = aw + (long)(w * 32 + R2) * 1024 + kc * 128;
#pragma unroll
      for (int half = 0; half < 2; ++half) {
        int g2 = half * 8 + gx;
        s8 pv = *(const s8*)((char*)Pw + R2 * 256 + ((g2 ^ (R2 & 7)) * 16));
        f4 lo, hi;
        lo.x = bf2f((u16)pv[0]); lo.y = bf2f((u16)pv[1]);
        lo.z = bf2f((u16)pv[2]); lo.w = bf2f((u16)pv[3]);
        hi.x = bf2f((u16)pv[4]); hi.y = bf2f((u16)pv[5]);
        hi.z = bf2f((u16)pv[6]); hi.w = bf2f((u16)pv[7]);
        *(f4*)(dst + g2 * 8)     = lo;
        *(f4*)(dst + g2 * 8 + 4) = hi;
      }
    }
  }

#pragma unroll
  for (int i = 0; i < 2; ++i)
#pragma unroll
    for (int j = 0; j < 4; ++j)
#pragma unroll
      for (int q = 0; q < 4; ++q) {
        int R = w * 32 + i * 16 + (lane >> 4) * 4 + q;
        int col = h * 64 + j * 16 + (lane & 15);
        ctxb[(long)(b * 1024 + qt * 128 + R) * 1024 + col] = (u16)bf16r(o_[i][j][q]);
      }
}

// ---------------------------------------------------------------------------
DEVI float blockSum(float v, float* sh) {
#pragma unroll
  for (int o = 32; o > 0; o >>= 1) v += __shfl_xor(v, o);
  int w = threadIdx.x >> 6;
  __syncthreads();
  if ((threadIdx.x & 63) == 0) sh[w] = v;
  __syncthreads();
  return (sh[0] + sh[1]) + (sh[2] + sh[3]);
}

// in = P0 + P1 + resid + bias[c]; LayerNorm(g,be); write fp32 and/or bf16.
template<bool RBF16>
__global__ __launch_bounds__(256)
void ln_combine(const float* __restrict__ P0, const float* __restrict__ P1,
                const void* __restrict__ resid, const float* __restrict__ bias,
                const float* __restrict__ g, const float* __restrict__ be,
                float* __restrict__ outf, u16* __restrict__ outb)
{
  __shared__ float sh[4];
  long row = blockIdx.x;
  int t = threadIdx.x;
  long off = row * 1024 + t * 4;
  f4 v = *(const f4*)(P0 + off);
  v += *(const f4*)(P1 + off);
  if constexpr (RBF16) {
    us4 rp = *(const us4*)((const u16*)resid + off);
    v.x += bf2f(rp.x); v.y += bf2f(rp.y); v.z += bf2f(rp.z); v.w += bf2f(rp.w);
  } else {
    v += *(const f4*)((const float*)resid + off);
  }
  v += *(const f4*)(bias + t * 4);
  float s = (v.x + v.y) + (v.z + v.w);
  s = blockSum(s, sh);
  float mu = s * (1.0f / 1024.0f);
  f4 d = v - mu;
  float s2 = (d.x * d.x + d.y * d.y) + (d.z * d.z + d.w * d.w);
  s2 = blockSum(s2, sh);
  float rs = rsqrtf(s2 * (1.0f / 1024.0f) + 1e-5f);
  f4 gg = *(const f4*)(g + t * 4);
  f4 bb = *(const f4*)(be + t * 4);
  f4 o = d * rs * gg + bb;
  if (outf) *(f4*)(outf + off) = o;
  if (outb) {
    us4 ob;
    ob.x = (u16)bf16r(o.x); ob.y = (u16)bf16r(o.y);
    ob.z = (u16)bf16r(o.z); ob.w = (u16)bf16r(o.w);
    *(us4*)(outb + off) = ob;
  }
}

// all five fp32->bf16 conversions in one launch
__global__ __launch_bounds__(256)
void cvt_all(const float* __restrict__ s0, const float* __restrict__ s1,
             const float* __restrict__ s2, const float* __restrict__ s3,
             const float* __restrict__ s4,
             u16* __restrict__ d0, u16* __restrict__ d1, u16* __restrict__ d2,
             u16* __restrict__ d3, u16* __restrict__ d4)
{
  int bi = blockIdx.x;
  const float* s; u16* d; int base;
  if      (bi < 2048) { s = s0; d = d0; base = bi; }
  else if (bi < 3584) { s = s1; d = d1; base = bi - 2048; }
  else if (bi < 4096) { s = s2; d = d2; base = bi - 3584; }
  else if (bi < 6144) { s = s3; d = d3; base = bi - 4096; }
  else                { s = s4; d = d4; base = bi - 6144; }
  long i = ((long)base * 256 + threadIdx.x) * 8;
  f4 a = *(const f4*)(s + i);
  f4 b = *(const f4*)(s + i + 4);
  *(s8*)(d + i) = cvt8(a, b);
}

// vt[bh][d][s] = qkvb[b, s, 2048 + h*64 + d]   (bf16)
__global__ __launch_bounds__(256)
void transpose_v(const u16* __restrict__ qkv, u16* __restrict__ vt) {
  __shared__ u16 tile[64][72];
  int blk = blockIdx.x, bh = blk >> 4, st = blk & 15;
  int b = bh >> 4, h = bh & 15, s0 = st * 64;
  const u16* gq = qkv + (long)b * 1024 * 3072 + 2048 + (long)h * 64;
  int t = threadIdx.x;
  int sl = t >> 4, dq = (t & 15) * 4;
#pragma unroll
  for (int it = 0; it < 4; ++it) {
    int s = it * 16 + sl;
    us4 v = *(const us4*)(gq + (long)(s0 + s) * 3072 + dq);
    tile[dq + 0][s] = v.x; tile[dq + 1][s] = v.y;
    tile[dq + 2][s] = v.z; tile[dq + 3][s] = v.w;
  }
  __syncthreads();
  u16* o = vt + (long)bh * 65536 + s0;
  int dl = t >> 4, sq = (t & 15) * 4;
#pragma unroll
  for (int it = 0; it < 4; ++it) {
    int d = it * 16 + dl;
    us4 v;
    v.x = tile[d][sq + 0]; v.y = tile[d][sq + 1];
    v.z = tile[d][sq + 2]; v.w = tile[d][sq + 3];
    *(us4*)(o + (long)d * 1024 + sq) = v;
  }
}

// ============================================================================
extern "C" void kernel_launch(void* const* d_in, const int* in_sizes, int n_in,
                              void* d_out, int out_size, void* d_ws, size_t ws_size,
                              hipStream_t stream)
{
  (void)in_sizes; (void)n_in; (void)out_size; (void)ws_size;
  const float* src   = (const float*)d_in[0];
  const float* w_in  = (const float*)d_in[1];
  const float* b_in  = (const float*)d_in[2];
  const float* w_out = (const float*)d_in[3];
  const float* b_out = (const float*)d_in[4];
  const float* w1    = (const float*)d_in[5];
  const float* b1    = (const float*)d_in[6];
  const float* w2    = (const float*)d_in[7];
  const float* b2    = (const float*)d_in[8];
  const float* g1    = (const float*)d_in[9];
  const float* be1   = (const float*)d_in[10];
  const float* g2    = (const float*)d_in[11];
  const float* be2   = (const float*)d_in[12];

  float* out   = (float*)d_out;
  float* attnW = out + (long)4 * 1024 * 1024;

  char* ws = (char*)d_ws;
  u16*   qkvb   = (u16*)(ws);                    // [4096,3072] bf16
  u16*   vtb    = (u16*)(ws + 25165824);
  u16*   srcb   = (u16*)(ws + 33554432);
  u16*   ctxb   = (u16*)(ws + 41943040);
  u16*   xb     = (u16*)(ws + 50331648);
  u16*   w_in_b = (u16*)(ws + 58720256);
  u16*   w_outb = (u16*)(ws + 65011712);
  u16*   w1b    = (u16*)(ws + 67108864);
  u16*   w2b    = (u16*)(ws + 75497472);
  u16*   h1b    = (u16*)(ws);                    // [4096,4096] bf16 [0,32M)
  float* wsf    = (float*)ws;
  float* Qp     = wsf;                           // Q0 [0,16M), Q1 [16,32M)
  float* Rp     = wsf + 20971520;                // R0 [80,96M), R1 [96,112M)

  // 0. conversions
  cvt_all<<<dim3(8192), 256, 0, stream>>>(src, w_in, w_out, w1, w2,
                                          srcb, w_in_b, w_outb, w1b, w2b);

  // 1. qkvb = bf16(src @ w_in^T + b_in), q-cols scaled by 0.125
  gemm128<<<dim3(24, 32), 256, 0, stream>>>(
      srcb, 1024, w_in_b, 1024, qkvb, 3072, b_in, 1024, 1024, 0.125f);

  // 2. vtb = V^T per (b,h)
  transpose_v<<<dim3(1024), 256, 0, stream>>>(qkvb, vtb);

  // 3. fused attention: attnW fp32 + ctxb bf16
  attn_fused<<<dim3(512), 256, 0, stream>>>(qkvb, vtb, attnW, ctxb);

  // 4. out-proj split-K=2 -> Q0,Q1 (qkvb/vtb region is dead; L3-resident)
  gemm128s<<<dim3(8, 32, 2), 256, 0, stream>>>(
      ctxb, 1024, 512, w_outb, 1024, 512, Qp, 1024, 512);

  // 5. xb = bf16(LN1(Q0+Q1+src+b_out))
  ln_combine<false><<<dim3(4096), 256, 0, stream>>>(
      Qp, Qp + 4194304, src, b_out, g1, be1, nullptr, xb);

  // 6. h1b = bf16(relu(x @ w1^T + b1))  (overwrites dead Q0/Q1)
  gemm256<<<dim3(16, 16), 512, 0, stream>>>(
      xb, 1024, w1b, 1024, h1b, 4096, b1, 1024, 1);

  // 7. FFN2 split-K=2 -> R0,R1
  gemm128s<<<dim3(8, 32, 2), 256, 0, stream>>>(
      h1b, 4096, 2048, w2b, 4096, 2048, Rp, 1024, 2048);

  // 8. out = LN2(R0+R1+xb+b2)  (fp32)
  ln_combine<true><<<dim3(4096), 256, 0, stream>>>(
      Rp, Rp + 4194304, xb, b2, g2, be2, out, nullptr);
}